// Round 6
// baseline (486.306 us; speedup 1.0000x reference)
//
#include <hip/hip_runtime.h>

#define D_DIRS 1296
#define K_PTS  64
#define R_RANK 16
#define F_SUB  408
#define DT_VAL (200.0f / 64.0f)

#define DIRS_PER_BLOCK 2
#define NBLOCKS (D_DIRS / DIRS_PER_BLOCK)   // 648

// ---------------------------------------------------------------------------
// accum: per block, 2 directions. Stage att/rad tiles in LDS, compute
// C = dt * inclusive-cumsum_k(att) block-locally, then accumulate
//   G[i,j]   += sum_k      conj(rad)_i * conj(att)_j
//   T[i,j,l] += sum_{k>=1} conj(rad)_i * conj(att)_j * C_l
// Thread t owns (i = t>>4, j = t&15); T[i,j,:] lives in 32 VGPRs.
// (Values cross-verified: identical results to a direct line-by-line mirror
//  of the reference in rounds 1/2 vs 5.)
// ---------------------------------------------------------------------------
__global__ __launch_bounds__(256) void accum_kernel(
    const float* __restrict__ att_r, const float* __restrict__ att_i,
    const float* __restrict__ rad_r, const float* __restrict__ rad_i,
    float* __restrict__ T_ws, float* __restrict__ G_ws)
{
    __shared__ float2 sAtt[K_PTS * R_RANK];  // [k*16 + l] = {re, im}
    __shared__ float2 sRad[K_PTS * R_RANK];
    __shared__ float2 sCum[K_PTS * R_RANK];  // C = dt * cumsum(att)

    const int t  = threadIdx.x;
    const int ri = t >> 4;       // rank index i (rad side)
    const int rj = t & 15;       // rank index j (att side)

    float accR[16], accI[16];
#pragma unroll
    for (int l = 0; l < 16; ++l) { accR[l] = 0.f; accI[l] = 0.f; }
    float gR = 0.f, gI = 0.f;

    for (int dd = 0; dd < DIRS_PER_BLOCK; ++dd) {
        const int d = blockIdx.x * DIRS_PER_BLOCK + dd;
        const int base = d * K_PTS * R_RANK;   // 1024 floats per array

        __syncthreads();   // protect LDS reuse across dd iterations
#pragma unroll
        for (int v = t; v < K_PTS * R_RANK; v += 256) {
            sAtt[v] = make_float2(att_r[base + v], att_i[base + v]);
            sRad[v] = make_float2(rad_r[base + v], rad_i[base + v]);
        }
        __syncthreads();

        // inclusive cumsum over k: 16 threads, one per rank l
        if (t < 16) {
            float sr = 0.f, si = 0.f;
            for (int k = 0; k < K_PTS; ++k) {
                float2 a = sAtt[k * 16 + t];
                sr += a.x; si += a.y;
                sCum[k * 16 + t] = make_float2(DT_VAL * sr, DT_VAL * si);
            }
        }
        __syncthreads();

        // k = 0: first order only
        {
            float2 a = sRad[ri];
            float2 b = sAtt[rj];
            gR += a.x * b.x - a.y * b.y;
            gI -= a.x * b.y + a.y * b.x;
        }
        // k >= 1: first + second order
        for (int k = 1; k < K_PTS; ++k) {
            float2 a = sRad[k * 16 + ri];
            float2 b = sAtt[k * 16 + rj];
            float wr = a.x * b.x - a.y * b.y;        // conj(rad)_i*conj(att)_j
            float wi = -(a.x * b.y + a.y * b.x);
            gR += wr; gI += wi;
#pragma unroll
            for (int l = 0; l < 16; ++l) {
                float2 c = sCum[k * 16 + l];
                accR[l] += wr * c.x - wi * c.y;
                accI[l] += wr * c.y + wi * c.x;
            }
        }
    }

    // global accumulation (T_ws/G_ws zeroed by hipMemsetAsync)
#pragma unroll
    for (int l = 0; l < 16; ++l) {
        atomicAdd(&T_ws[(t * 16 + l) * 2 + 0], accR[l]);
        atomicAdd(&T_ws[(t * 16 + l) * 2 + 1], accI[l]);
    }
    atomicAdd(&G_ws[t * 2 + 0], gR);
    atomicAdd(&G_ws[t * 2 + 1], gI);
}

// ---------------------------------------------------------------------------
// contract:  csi[f] = (dt/D) * sum_{i,j} (G[i,j] + sum_l T[i,j,l] f_l) f_i f_j
// One block per f; thread t owns (i,j); block reduction.
// OUTPUT: float32 PLANAR — out[f] = re(csi_f), out[F_SUB + f] = im(csi_f).
// ---------------------------------------------------------------------------
__global__ __launch_bounds__(256) void contract_kernel(
    const float* __restrict__ fr, const float* __restrict__ fi,
    const float* __restrict__ T_ws, const float* __restrict__ G_ws,
    float* __restrict__ out)
{
    const int f = blockIdx.x;
    const int t = threadIdx.x;
    const int i = t >> 4;
    const int j = t & 15;

    __shared__ float sfr[16], sfi[16];
    if (t < 16) {
        sfr[t] = fr[f * R_RANK + t];
        sfi[t] = fi[f * R_RANK + t];
    }
    __syncthreads();

    float fir = sfr[i], fii = sfi[i];
    float fjr = sfr[j], fji = sfi[j];
    float mr = fir * fjr - fii * fji;   // f_i * f_j
    float mi = fir * fji + fii * fjr;

    float Sr = G_ws[t * 2 + 0];
    float Si = G_ws[t * 2 + 1];
#pragma unroll
    for (int l = 0; l < 16; ++l) {
        float Tr = T_ws[(t * 16 + l) * 2 + 0];
        float Ti = T_ws[(t * 16 + l) * 2 + 1];
        float flr = sfr[l], fli = sfi[l];
        Sr += Tr * flr - Ti * fli;
        Si += Tr * fli + Ti * flr;
    }

    float vr = Sr * mr - Si * mi;
    float vi = Sr * mi + Si * mr;

    // 64-lane wave reduction, then cross-wave via LDS
#pragma unroll
    for (int off = 32; off >= 1; off >>= 1) {
        vr += __shfl_down(vr, off, 64);
        vi += __shfl_down(vi, off, 64);
    }
    __shared__ float red[8];
    const int lane = t & 63, w = t >> 6;
    if (lane == 0) { red[w * 2] = vr; red[w * 2 + 1] = vi; }
    __syncthreads();
    if (t == 0) {
        float rr = red[0] + red[2] + red[4] + red[6];
        float ii = red[1] + red[3] + red[5] + red[7];
        const float scale = DT_VAL / (float)D_DIRS;
        out[f]         = rr * scale;   // planar: re block
        out[F_SUB + f] = ii * scale;   // planar: im block
    }
}

// ---------------------------------------------------------------------------
extern "C" void kernel_launch(void* const* d_in, const int* in_sizes, int n_in,
                              void* d_out, int out_size, void* d_ws, size_t ws_size,
                              hipStream_t stream)
{
    const float* att_r = (const float*)d_in[0];
    const float* att_i = (const float*)d_in[1];
    const float* rad_r = (const float*)d_in[2];
    const float* rad_i = (const float*)d_in[3];
    const float* fr    = (const float*)d_in[4];
    const float* fi    = (const float*)d_in[5];

    float* ws   = (float*)d_ws;
    float* T_ws = ws;                 // 8192 floats (4096 complex)
    float* G_ws = ws + 8192;          // 512 floats  (256 complex)

    // zero the accumulation buffers (ws is re-poisoned before every call)
    hipMemsetAsync(T_ws, 0, (8192 + 512) * sizeof(float), stream);

    accum_kernel<<<NBLOCKS, 256, 0, stream>>>(
        att_r, att_i, rad_r, rad_i, T_ws, G_ws);

    contract_kernel<<<F_SUB, 256, 0, stream>>>(
        fr, fi, T_ws, G_ws, (float*)d_out);
}

// Round 8
// 191.507 us; speedup vs baseline: 2.5394x; 2.5394x over previous
//
#include <hip/hip_runtime.h>

#define D_DIRS 1296
#define K_PTS  64
#define R_RANK 16
#define F_SUB  408
#define DT_VAL (200.0f / 64.0f)

#define DIRS_PER_BLOCK 2
#define NBLOCKS (D_DIRS / DIRS_PER_BLOCK)   // 648
#define PARTIAL_FLOATS 8704                 // 8192 T + 512 G per block
#define PBUF_BYTES ((size_t)NBLOCKS * PARTIAL_FLOATS * 4)

// ---------------------------------------------------------------------------
// accum core: per block, 2 directions. Stage att/rad tiles in LDS, compute
// C = dt * inclusive-cumsum_k(att) block-locally, then accumulate
//   G[i,j]   += sum_k      conj(rad)_i * conj(att)_j
//   T[i,j,l] += sum_{k>=1} conj(rad)_i * conj(att)_j * C_l
// Thread t owns (i = t>>4, j = t&15); T[i,j,:] lives in 32 VGPRs.
// ---------------------------------------------------------------------------
template <bool USE_PARTIALS>
__global__ __launch_bounds__(256) void accum_kernel_t(
    const float* __restrict__ att_r, const float* __restrict__ att_i,
    const float* __restrict__ rad_r, const float* __restrict__ rad_i,
    float* __restrict__ T_ws, float* __restrict__ G_ws,
    float* __restrict__ pbuf)
{
    __shared__ float2 sAtt[K_PTS * R_RANK];  // [k*16 + l] = {re, im}
    __shared__ float2 sRad[K_PTS * R_RANK];
    __shared__ float2 sCum[K_PTS * R_RANK];  // C = dt * cumsum(att)

    const int t  = threadIdx.x;
    const int ri = t >> 4;       // rank index i (rad side)
    const int rj = t & 15;       // rank index j (att side)

    float accR[16], accI[16];
#pragma unroll
    for (int l = 0; l < 16; ++l) { accR[l] = 0.f; accI[l] = 0.f; }
    float gR = 0.f, gI = 0.f;

    for (int dd = 0; dd < DIRS_PER_BLOCK; ++dd) {
        const int d = blockIdx.x * DIRS_PER_BLOCK + dd;
        const int base = d * K_PTS * R_RANK;   // 1024 floats per array

        __syncthreads();   // protect LDS reuse across dd iterations
#pragma unroll
        for (int v = t; v < K_PTS * R_RANK; v += 256) {
            sAtt[v] = make_float2(att_r[base + v], att_i[base + v]);
            sRad[v] = make_float2(rad_r[base + v], rad_i[base + v]);
        }
        __syncthreads();

        // inclusive cumsum over k: 16 threads, one per rank l
        if (t < 16) {
            float sr = 0.f, si = 0.f;
            for (int k = 0; k < K_PTS; ++k) {
                float2 a = sAtt[k * 16 + t];
                sr += a.x; si += a.y;
                sCum[k * 16 + t] = make_float2(DT_VAL * sr, DT_VAL * si);
            }
        }
        __syncthreads();

        // k = 0: first order only
        {
            float2 a = sRad[ri];
            float2 b = sAtt[rj];
            gR += a.x * b.x - a.y * b.y;
            gI -= a.x * b.y + a.y * b.x;
        }
        // k >= 1: first + second order
        for (int k = 1; k < K_PTS; ++k) {
            float2 a = sRad[k * 16 + ri];
            float2 b = sAtt[k * 16 + rj];
            float wr = a.x * b.x - a.y * b.y;        // conj(rad)_i*conj(att)_j
            float wi = -(a.x * b.y + a.y * b.x);
            gR += wr; gI += wi;
#pragma unroll
            for (int l = 0; l < 16; ++l) {
                float2 c = sCum[k * 16 + l];
                accR[l] += wr * c.x - wi * c.y;
                accI[l] += wr * c.y + wi * c.x;
            }
        }
    }

    if (USE_PARTIALS) {
        // Non-atomic per-block partials: thread t owns 32 contiguous floats
        // at pbuf[blk*8704 + t*32]  (layout == T_ws indexing: (t*16+l)*2+c),
        // plus a float2 in the G section at 8192 + t*2.
        float4* pT = (float4*)(pbuf + (size_t)blockIdx.x * PARTIAL_FLOATS + t * 32);
#pragma unroll
        for (int v = 0; v < 8; ++v) {
            pT[v] = make_float4(accR[v * 2],     accI[v * 2],
                                accR[v * 2 + 1], accI[v * 2 + 1]);
        }
        float2* pG = (float2*)(pbuf + (size_t)blockIdx.x * PARTIAL_FLOATS + 8192 + t * 2);
        *pG = make_float2(gR, gI);
    } else {
        // Fallback: device atomics (T_ws/G_ws zeroed by hipMemsetAsync)
#pragma unroll
        for (int l = 0; l < 16; ++l) {
            atomicAdd(&T_ws[(t * 16 + l) * 2 + 0], accR[l]);
            atomicAdd(&T_ws[(t * 16 + l) * 2 + 1], accI[l]);
        }
        atomicAdd(&G_ws[t * 2 + 0], gR);
        atomicAdd(&G_ws[t * 2 + 1], gI);
    }
}

// ---------------------------------------------------------------------------
// reduce: TG_out[e] = sum over 648 blocks of pbuf[b*8704 + e]; T_ws and G_ws
// are contiguous (G_ws = T_ws + 8192) so one flat write covers both.
// Coalesced: consecutive threads read/write consecutive e.
// ---------------------------------------------------------------------------
__global__ __launch_bounds__(256) void reduce_kernel(
    const float* __restrict__ pbuf, float* __restrict__ TG_out)
{
    int e = blockIdx.x * 256 + threadIdx.x;
    if (e >= PARTIAL_FLOATS) return;
    float s = 0.f;
    const float* p = pbuf + e;
#pragma unroll 8
    for (int b = 0; b < NBLOCKS; ++b)
        s += p[(size_t)b * PARTIAL_FLOATS];
    TG_out[e] = s;
}

// ---------------------------------------------------------------------------
// contract:  csi[f] = (dt/D) * sum_{i,j} (G[i,j] + sum_l T[i,j,l] f_l) f_i f_j
// One block per f; thread t owns (i,j); block reduction.
// OUTPUT: float32 PLANAR — out[f] = re(csi_f), out[F_SUB + f] = im(csi_f).
// ---------------------------------------------------------------------------
__global__ __launch_bounds__(256) void contract_kernel(
    const float* __restrict__ fr, const float* __restrict__ fi,
    const float* __restrict__ T_ws, const float* __restrict__ G_ws,
    float* __restrict__ out)
{
    const int f = blockIdx.x;
    const int t = threadIdx.x;
    const int i = t >> 4;
    const int j = t & 15;

    __shared__ float sfr[16], sfi[16];
    if (t < 16) {
        sfr[t] = fr[f * R_RANK + t];
        sfi[t] = fi[f * R_RANK + t];
    }
    __syncthreads();

    float fir = sfr[i], fii = sfi[i];
    float fjr = sfr[j], fji = sfi[j];
    float mr = fir * fjr - fii * fji;   // f_i * f_j
    float mi = fir * fji + fii * fjr;

    float Sr = G_ws[t * 2 + 0];
    float Si = G_ws[t * 2 + 1];
#pragma unroll
    for (int l = 0; l < 16; ++l) {
        float Tr = T_ws[(t * 16 + l) * 2 + 0];
        float Ti = T_ws[(t * 16 + l) * 2 + 1];
        float flr = sfr[l], fli = sfi[l];
        Sr += Tr * flr - Ti * fli;
        Si += Tr * fli + Ti * flr;
    }

    float vr = Sr * mr - Si * mi;
    float vi = Sr * mi + Si * mr;

    // 64-lane wave reduction, then cross-wave via LDS
#pragma unroll
    for (int off = 32; off >= 1; off >>= 1) {
        vr += __shfl_down(vr, off, 64);
        vi += __shfl_down(vi, off, 64);
    }
    __shared__ float red[8];
    const int lane = t & 63, w = t >> 6;
    if (lane == 0) { red[w * 2] = vr; red[w * 2 + 1] = vi; }
    __syncthreads();
    if (t == 0) {
        float rr = red[0] + red[2] + red[4] + red[6];
        float ii = red[1] + red[3] + red[5] + red[7];
        const float scale = DT_VAL / (float)D_DIRS;
        out[f]         = rr * scale;   // planar: re block
        out[F_SUB + f] = ii * scale;   // planar: im block
    }
}

// ---------------------------------------------------------------------------
extern "C" void kernel_launch(void* const* d_in, const int* in_sizes, int n_in,
                              void* d_out, int out_size, void* d_ws, size_t ws_size,
                              hipStream_t stream)
{
    const float* att_r = (const float*)d_in[0];
    const float* att_i = (const float*)d_in[1];
    const float* rad_r = (const float*)d_in[2];
    const float* rad_i = (const float*)d_in[3];
    const float* fr    = (const float*)d_in[4];
    const float* fi    = (const float*)d_in[5];

    float* ws   = (float*)d_ws;
    float* T_ws = ws;                 // 8192 floats (4096 complex)
    float* G_ws = ws + 8192;          // 512 floats  (256 complex)  (contiguous)
    float* pbuf = ws + PARTIAL_FLOATS;

    const bool use_partials =
        ws_size >= (size_t)(PARTIAL_FLOATS) * 4 + PBUF_BYTES;

    if (use_partials) {
        accum_kernel_t<true><<<NBLOCKS, 256, 0, stream>>>(
            att_r, att_i, rad_r, rad_i, T_ws, G_ws, pbuf);
        reduce_kernel<<<(PARTIAL_FLOATS + 255) / 256, 256, 0, stream>>>(
            pbuf, T_ws);
    } else {
        hipMemsetAsync(T_ws, 0, PARTIAL_FLOATS * sizeof(float), stream);
        accum_kernel_t<false><<<NBLOCKS, 256, 0, stream>>>(
            att_r, att_i, rad_r, rad_i, T_ws, G_ws, pbuf);
    }

    contract_kernel<<<F_SUB, 256, 0, stream>>>(
        fr, fi, T_ws, G_ws, (float*)d_out);
}

// Round 9
// 167.058 us; speedup vs baseline: 2.9110x; 1.1464x over previous
//
#include <hip/hip_runtime.h>

#define D_DIRS 1296
#define K_PTS  64
#define R_RANK 16
#define F_SUB  408
#define DT_VAL (200.0f / 64.0f)

#define NBLOCKS (D_DIRS / 2)                // 648 blocks, 2 dirs each (parallel halves)
#define PARTIAL_FLOATS 8704                 // 8192 T + 512 G per slab
#define RED_CHUNKS 12                       // 648 = 12 * 54
#define SLABS_PER_CHUNK (NBLOCKS / RED_CHUNKS)
#define NEED_BYTES ((size_t)(1 + RED_CHUNKS + NBLOCKS) * PARTIAL_FLOATS * 4)

// ---------------------------------------------------------------------------
// accum: 512 threads = 2 halves; half h owns direction d = 2*blk + h.
// Reverse-cumsum formulation (no sCum, no serial phase):
//   S(k) = sum_{k'>=max(k,1)} w(k'),  w = conj(rad)_i * conj(att)_j
//   T[i,j,l] = dt * sum_k att_l(k) * S(k)     (plain att: C = dt*cumsum(att))
//   G[i,j]   = S(after k=1) + w(0)
// Thread t2 in its half owns (i = t2>>4, j = t2&15); acc in 32 VGPRs.
// ---------------------------------------------------------------------------
union alignas(16) SMem {
    struct { float2 att[2][K_PTS * R_RANK]; float2 rad[2][K_PTS * R_RANK]; } tiles; // 32 KB
    float red[PARTIAL_FLOATS];                                                      // 34816 B
};

template <bool USE_PARTIALS>
__global__ __launch_bounds__(512) void accum_kernel_t(
    const float* __restrict__ att_r, const float* __restrict__ att_i,
    const float* __restrict__ rad_r, const float* __restrict__ rad_i,
    float* __restrict__ T_ws, float* __restrict__ pbuf)
{
    __shared__ SMem sm;

    const int t  = threadIdx.x;          // 0..511
    const int h  = t >> 8;               // half: 0 or 1
    const int t2 = t & 255;
    const int ri = t2 >> 4;
    const int rj = t2 & 15;
    const int d  = blockIdx.x * 2 + h;
    const int base = d * K_PTS * R_RANK;

    float2* sA = sm.tiles.att[h];
    float2* sR = sm.tiles.rad[h];
#pragma unroll
    for (int v = t2; v < K_PTS * R_RANK; v += 256) {
        sA[v] = make_float2(att_r[base + v], att_i[base + v]);
        sR[v] = make_float2(rad_r[base + v], rad_i[base + v]);
    }
    __syncthreads();

    float accR[16], accI[16];
#pragma unroll
    for (int l = 0; l < 16; ++l) { accR[l] = 0.f; accI[l] = 0.f; }
    float Sr = 0.f, Si = 0.f;

    for (int k = K_PTS - 1; k >= 1; --k) {
        float2 a = sR[k * 16 + ri];
        float2 b = sA[k * 16 + rj];
        Sr += a.x * b.x - a.y * b.y;          // S += conj(rad)_i*conj(att)_j
        Si -= a.x * b.y + a.y * b.x;
#pragma unroll
        for (int q = 0; q < 8; ++q) {
            float4 c = *reinterpret_cast<const float4*>(&sA[k * 16 + q * 2]);
            accR[q * 2]     += Sr * c.x - Si * c.y;
            accI[q * 2]     += Sr * c.y + Si * c.x;
            accR[q * 2 + 1] += Sr * c.z - Si * c.w;
            accI[q * 2 + 1] += Sr * c.w + Si * c.z;
        }
    }
    // k = 0: T-term uses S(0) = S(1) (current S, w0 excluded); G = S + w0
#pragma unroll
    for (int q = 0; q < 8; ++q) {
        float4 c = *reinterpret_cast<const float4*>(&sA[q * 2]);
        accR[q * 2]     += Sr * c.x - Si * c.y;
        accI[q * 2]     += Sr * c.y + Si * c.x;
        accR[q * 2 + 1] += Sr * c.z - Si * c.w;
        accI[q * 2 + 1] += Sr * c.w + Si * c.z;
    }
    float2 a0 = sR[ri], b0 = sA[rj];
    float gR = Sr + (a0.x * b0.x - a0.y * b0.y);
    float gI = Si - (a0.x * b0.y + a0.y * b0.x);

    // ---- merge half 1 into half 0 via LDS, then emit ----
    __syncthreads();                      // done with tiles
    if (h == 1) {
        float4* r4 = (float4*)sm.red;     // T region: 2048 float4, swizzled slot
#pragma unroll
        for (int q = 0; q < 8; ++q) {
            r4[t2 * 8 + (q ^ (t2 & 7))] =
                make_float4(accR[q * 2], accI[q * 2], accR[q * 2 + 1], accI[q * 2 + 1]);
        }
        sm.red[8192 + t2 * 2 + 0] = gR;
        sm.red[8192 + t2 * 2 + 1] = gI;
    }
    __syncthreads();
    if (h == 0) {
        if (USE_PARTIALS) {
            float4* slabT = (float4*)(pbuf + (size_t)blockIdx.x * PARTIAL_FLOATS);
            const float4* r4 = (const float4*)sm.red;
#pragma unroll
            for (int q = 0; q < 8; ++q) {
                float4 o = r4[t2 * 8 + (q ^ (t2 & 7))];
                slabT[t2 * 8 + q] = make_float4(
                    (accR[q * 2]     + o.x) * DT_VAL, (accI[q * 2]     + o.y) * DT_VAL,
                    (accR[q * 2 + 1] + o.z) * DT_VAL, (accI[q * 2 + 1] + o.w) * DT_VAL);
            }
            float2* slabG = (float2*)(pbuf + (size_t)blockIdx.x * PARTIAL_FLOATS + 8192);
            slabG[t2] = make_float2(gR + sm.red[8192 + t2 * 2],
                                    gI + sm.red[8192 + t2 * 2 + 1]);
        } else {
            const float4* r4 = (const float4*)sm.red;
#pragma unroll
            for (int q = 0; q < 8; ++q) {
                float4 o = r4[t2 * 8 + (q ^ (t2 & 7))];
                atomicAdd(&T_ws[(t2 * 8 + q) * 4 + 0], (accR[q * 2]     + o.x) * DT_VAL);
                atomicAdd(&T_ws[(t2 * 8 + q) * 4 + 1], (accI[q * 2]     + o.y) * DT_VAL);
                atomicAdd(&T_ws[(t2 * 8 + q) * 4 + 2], (accR[q * 2 + 1] + o.z) * DT_VAL);
                atomicAdd(&T_ws[(t2 * 8 + q) * 4 + 3], (accI[q * 2 + 1] + o.w) * DT_VAL);
            }
            atomicAdd(&T_ws[8192 + t2 * 2 + 0], gR + sm.red[8192 + t2 * 2]);
            atomicAdd(&T_ws[8192 + t2 * 2 + 1], gI + sm.red[8192 + t2 * 2 + 1]);
        }
    }
}

// ---------------------------------------------------------------------------
// reduce, 2-stage. Stage 1: chunk c sums 54 slabs -> red1[c]. Stage 2: sum 12.
// ---------------------------------------------------------------------------
__global__ __launch_bounds__(256) void reduce1_kernel(
    const float* __restrict__ pbuf, float* __restrict__ red1)
{
    int e = blockIdx.x * 256 + threadIdx.x;              // 34*256 == 8704
    float s = 0.f;
    const float* p = pbuf + (size_t)blockIdx.y * SLABS_PER_CHUNK * PARTIAL_FLOATS + e;
#pragma unroll 6
    for (int b = 0; b < SLABS_PER_CHUNK; ++b)
        s += p[(size_t)b * PARTIAL_FLOATS];
    red1[blockIdx.y * PARTIAL_FLOATS + e] = s;
}

__global__ __launch_bounds__(256) void reduce2_kernel(
    const float* __restrict__ red1, float* __restrict__ TG_out)
{
    int e = blockIdx.x * 256 + threadIdx.x;
    float s = 0.f;
#pragma unroll
    for (int c = 0; c < RED_CHUNKS; ++c)
        s += red1[c * PARTIAL_FLOATS + e];
    TG_out[e] = s;
}

// ---------------------------------------------------------------------------
// contract:  csi[f] = (dt/D) * sum_{i,j} (G[i,j] + sum_l T[i,j,l] f_l) f_i f_j
// OUTPUT: float32 PLANAR — out[f] = re, out[F_SUB + f] = im.
// ---------------------------------------------------------------------------
__global__ __launch_bounds__(256) void contract_kernel(
    const float* __restrict__ fr, const float* __restrict__ fi,
    const float* __restrict__ T_ws, const float* __restrict__ G_ws,
    float* __restrict__ out)
{
    const int f = blockIdx.x;
    const int t = threadIdx.x;
    const int i = t >> 4;
    const int j = t & 15;

    __shared__ float sfr[16], sfi[16];
    if (t < 16) {
        sfr[t] = fr[f * R_RANK + t];
        sfi[t] = fi[f * R_RANK + t];
    }
    __syncthreads();

    float fir = sfr[i], fii = sfi[i];
    float fjr = sfr[j], fji = sfi[j];
    float mr = fir * fjr - fii * fji;
    float mi = fir * fji + fii * fjr;

    float Sr = G_ws[t * 2 + 0];
    float Si = G_ws[t * 2 + 1];
#pragma unroll
    for (int l = 0; l < 16; ++l) {
        float Tr = T_ws[(t * 16 + l) * 2 + 0];
        float Ti = T_ws[(t * 16 + l) * 2 + 1];
        float flr = sfr[l], fli = sfi[l];
        Sr += Tr * flr - Ti * fli;
        Si += Tr * fli + Ti * flr;
    }

    float vr = Sr * mr - Si * mi;
    float vi = Sr * mi + Si * mr;

#pragma unroll
    for (int off = 32; off >= 1; off >>= 1) {
        vr += __shfl_down(vr, off, 64);
        vi += __shfl_down(vi, off, 64);
    }
    __shared__ float red[8];
    const int lane = t & 63, w = t >> 6;
    if (lane == 0) { red[w * 2] = vr; red[w * 2 + 1] = vi; }
    __syncthreads();
    if (t == 0) {
        float rr = red[0] + red[2] + red[4] + red[6];
        float ii = red[1] + red[3] + red[5] + red[7];
        const float scale = DT_VAL / (float)D_DIRS;
        out[f]         = rr * scale;
        out[F_SUB + f] = ii * scale;
    }
}

// ---------------------------------------------------------------------------
extern "C" void kernel_launch(void* const* d_in, const int* in_sizes, int n_in,
                              void* d_out, int out_size, void* d_ws, size_t ws_size,
                              hipStream_t stream)
{
    const float* att_r = (const float*)d_in[0];
    const float* att_i = (const float*)d_in[1];
    const float* rad_r = (const float*)d_in[2];
    const float* rad_i = (const float*)d_in[3];
    const float* fr    = (const float*)d_in[4];
    const float* fi    = (const float*)d_in[5];

    float* ws   = (float*)d_ws;
    float* T_ws = ws;                                    // 8704 floats (T then G)
    float* G_ws = ws + 8192;
    float* red1 = ws + PARTIAL_FLOATS;                   // 12 * 8704 floats
    float* pbuf = ws + (1 + RED_CHUNKS) * PARTIAL_FLOATS;

    const bool use_partials = ws_size >= NEED_BYTES;

    if (use_partials) {
        accum_kernel_t<true><<<NBLOCKS, 512, 0, stream>>>(
            att_r, att_i, rad_r, rad_i, T_ws, pbuf);
        reduce1_kernel<<<dim3(PARTIAL_FLOATS / 256, RED_CHUNKS), 256, 0, stream>>>(
            pbuf, red1);
        reduce2_kernel<<<PARTIAL_FLOATS / 256, 256, 0, stream>>>(red1, T_ws);
    } else {
        hipMemsetAsync(T_ws, 0, PARTIAL_FLOATS * sizeof(float), stream);
        accum_kernel_t<false><<<NBLOCKS, 512, 0, stream>>>(
            att_r, att_i, rad_r, rad_i, T_ws, pbuf);
    }

    contract_kernel<<<F_SUB, 256, 0, stream>>>(
        fr, fi, T_ws, G_ws, (float*)d_out);
}